// Round 5
// baseline (327.910 us; speedup 1.0000x reference)
//
#include <hip/hip_runtime.h>
#include <stdint.h>

// Problem constants (fixed by the reference)
#define N_TOK 8192
#define IN_F 4096
#define OUT_F 4096
#define BS 256
#define ABPI 5
#define NFLAT 80          // 16 output blocks x 5 slots = all (g,a) pairs

typedef __attribute__((ext_vector_type(8))) short short8;    // 8 bf16 = 4 VGPRs (MFMA A/B frag)
typedef __attribute__((ext_vector_type(4))) float floatx4;   // MFMA C/D frag
typedef __attribute__((ext_vector_type(4))) unsigned short ushort4v;

__device__ __forceinline__ unsigned short f2bf(float f) {
  union { float f; unsigned int u; } v; v.f = f;
  unsigned int r = v.u + 0x7FFFu + ((v.u >> 16) & 1u);   // RNE
  return (unsigned short)(r >> 16);
}

__device__ __forceinline__ void async16(const void* g, void* l) {
  __builtin_amdgcn_global_load_lds((const __attribute__((address_space(1))) void*)g,
                                   (__attribute__((address_space(3))) void*)l, 16, 0, 0);
}

// ---------------- kernel 1: x fp32 -> bf16 (pure-coalesced grid-stride) -------
__global__ void cvt_x_kernel(const float4* __restrict__ x, ushort4v* __restrict__ xb) {
  int idx = blockIdx.x * 256 + threadIdx.x;       // one float4 -> ushort4 per iter
  const int stride = 2048 * 256;
  #pragma unroll
  for (int i = 0; i < 16; ++i, idx += stride) {   // 8192*4096/4 = 16 * 2048*256
    float4 a = x[idx];
    ushort4v o;
    o[0] = f2bf(a.x); o[1] = f2bf(a.y); o[2] = f2bf(a.z); o[3] = f2bf(a.w);
    xb[idx] = o;
  }
}

// ---------------- kernel 2: weight fp32 -> bf16, transposed per (g,a) block ----
__global__ void cvt_w_kernel(const float* __restrict__ w, unsigned short* __restrict__ wt) {
  __shared__ unsigned short tile[64][68];
  int b = blockIdx.x;
  int fi = b >> 4;
  int t  = b & 15;
  int k0 = (t >> 2) * 64, o0 = (t & 3) * 64;
  int g = fi / ABPI, a = fi % ABPI;
  int tid = threadIdx.x;
  int tr = tid >> 4, tc = tid & 15;
  #pragma unroll
  for (int i = 0; i < 4; ++i) {
    int k = k0 + i * 16 + tr;
    const float* src = w + (size_t)(g * 256 + k) * (ABPI * BS) + a * BS + o0 + tc * 4;
    float4 v = *(const float4*)src;
    tile[tc * 4 + 0][i * 16 + tr] = f2bf(v.x);
    tile[tc * 4 + 1][i * 16 + tr] = f2bf(v.y);
    tile[tc * 4 + 2][i * 16 + tr] = f2bf(v.z);
    tile[tc * 4 + 3][i * 16 + tr] = f2bf(v.w);
  }
  __syncthreads();
  #pragma unroll
  for (int i = 0; i < 4; ++i) {
    int o = i * 16 + tr;
    unsigned short* dst = wt + (size_t)fi * (BS * BS) + (size_t)(o0 + o) * BS + k0 + tc * 4;
    *(ushort4v*)dst = *(const ushort4v*)&tile[o][tc * 4];
  }
}

// ---------------- kernel 3: butterfly block-sparse GEMM ------------------------
// 256x256 tile, 8 waves (2M x 4N), per-wave 128x64 output, BK=64, DOUBLE-buffered
// LDS (2 x 64 KiB), 1 block/CU (LDS-limited). ONE barrier per K-tile:
// within a tile the buffers are stable, so phases are separated only by
// counted per-wave lgkmcnt waits and ds_read bursts OVERLAP the MFMA bursts.
// Per tile: stage 8 t+1 loads; issue 16 ds_reads (A-half0,B01,B23);
// lgkm(4) -> P1 (af x bf01); lgkm(0) -> P2 (af x bf23); fence; issue A-half1
// into af; lgkm(0) -> P3 (af x bf23), P4 (af x bf01); vmcnt(0); barrier.
// Hazards at the single barrier: all reads of tile t complete before it
// (last lgkm(0) precedes it); stages into this buffer (t+2) issue after it.
// vmcnt(0) drains loads issued ~2500 cyc earlier (free), then barrier
// publishes them to all waves.

#define BM 256
#define BN 256
#define BK 64
#define ABYTES 32768              // 256 rows x 128 B
#define BUFBYTES 65536            // A + B
#define SMEM_TOTAL 131072         // 2 buffers

__device__ __forceinline__ void ld_half_A(const char* p, int c0, int c1, short8 (&af)[4][2]) {
  #pragma unroll
  for (int mt = 0; mt < 4; ++mt) {
    const char* q = p + mt * 2048;
    af[mt][0] = *(const short8*)(q + c0);
    af[mt][1] = *(const short8*)(q + c1);
  }
}

__device__ __forceinline__ void ld_pair_B(const char* p, int c0, int c1, short8 (&bf)[2][2]) {
  #pragma unroll
  for (int nt = 0; nt < 2; ++nt) {
    const char* q = p + nt * 2048;
    bf[nt][0] = *(const short8*)(q + c0);
    bf[nt][1] = *(const short8*)(q + c1);
  }
}

__device__ __forceinline__ void mma16(const short8 (&af)[4][2], const short8 (&bf)[2][2],
                                      floatx4 (&acc)[8][4], int mb, int nb) {
  #pragma unroll
  for (int mt = 0; mt < 4; ++mt)
    #pragma unroll
    for (int nt = 0; nt < 2; ++nt) {
      acc[mb + mt][nb + nt] =
          __builtin_amdgcn_mfma_f32_16x16x32_bf16(af[mt][0], bf[nt][0], acc[mb + mt][nb + nt], 0, 0, 0);
      acc[mb + mt][nb + nt] =
          __builtin_amdgcn_mfma_f32_16x16x32_bf16(af[mt][1], bf[nt][1], acc[mb + mt][nb + nt], 0, 0, 0);
    }
}

#define KTILE(tt, Ab, Bb, Asd, Bsd, DOSTAGE, LAST)                              \
  do {                                                                          \
    if (DOSTAGE) {                                                              \
      const int u = (tt) + 1, su = u >> 2, ku = (u & 3) * 64;                   \
      const int uA = gcol[su] + ku, uB = wbase[su] + ku;                        \
      async16(pA0 + uA, (Asd)         + tid16);                                 \
      async16(pA1 + uA, (Asd) +  8192 + tid16);                                 \
      async16(pA2 + uA, (Asd) + 16384 + tid16);                                 \
      async16(pA3 + uA, (Asd) + 24576 + tid16);                                 \
      async16(pB0 + uB, (Bsd)         + tid16);                                 \
      async16(pB1 + uB, (Bsd) +  8192 + tid16);                                 \
      async16(pB2 + uB, (Bsd) + 16384 + tid16);                                 \
      async16(pB3 + uB, (Bsd) + 24576 + tid16);                                 \
    }                                                                           \
    ld_half_A((Ab) + rAb, c0, c1, af);            /* 8 ds_read_b128 */          \
    ld_pair_B((Bb) + rBb, c0, c1, bf01);          /* 4 */                       \
    ld_pair_B((Bb) + rBb + 4096, c0, c1, bf23);   /* 4 */                       \
    asm volatile("s_waitcnt lgkmcnt(4)" ::: "memory");  /* A-half0+B01 done */  \
    __builtin_amdgcn_sched_barrier(0);                                          \
    __builtin_amdgcn_s_setprio(1);                                              \
    mma16(af, bf01, acc, 0, 0);                   /* P1, B23 still in flight */ \
    __builtin_amdgcn_s_setprio(0);                                              \
    asm volatile("s_waitcnt lgkmcnt(0)" ::: "memory");                          \
    __builtin_amdgcn_sched_barrier(0);                                          \
    __builtin_amdgcn_s_setprio(1);                                              \
    mma16(af, bf23, acc, 0, 2);                   /* P2 */                      \
    __builtin_amdgcn_s_setprio(0);                                              \
    __builtin_amdgcn_sched_barrier(0);            /* A-half1 reads stay below */\
    ld_half_A((Ab) + rAb + 8192, c0, c1, af);     /* 8, reuse af regs */        \
    asm volatile("s_waitcnt lgkmcnt(0)" ::: "memory");                          \
    __builtin_amdgcn_sched_barrier(0);                                          \
    __builtin_amdgcn_s_setprio(1);                                              \
    mma16(af, bf23, acc, 4, 2);                   /* P3 */                      \
    mma16(af, bf01, acc, 4, 0);                   /* P4 (register reuse) */     \
    __builtin_amdgcn_s_setprio(0);                                              \
    if (DOSTAGE) {                                                              \
      asm volatile("s_waitcnt vmcnt(0)" ::: "memory");  /* t+1 staged (old) */  \
      __builtin_amdgcn_sched_barrier(0);                                        \
      __builtin_amdgcn_s_barrier();               /* publish t+1; free t-1 */   \
    } else if (!(LAST)) {                                                       \
      __builtin_amdgcn_s_barrier();                                             \
    }                                                                           \
  } while (0)

__global__ __launch_bounds__(512, 2)
void bfly_gemm(const unsigned short* __restrict__ xb,   // [8192][4096] bf16
               const unsigned short* __restrict__ wt,   // [80][256 o][256 k] bf16
               const int* __restrict__ fidx,            // [16][5]
               float* __restrict__ out)                 // [8192][4096] fp32
{
  extern __shared__ __align__(16) char smem[];
  char* const b0A = smem;
  char* const b0B = b0A + ABYTES;
  char* const b1A = smem + BUFBYTES;
  char* const b1B = b1A + ABYTES;

  const int tid = threadIdx.x;
  // 512 blocks; bijective XCD swizzle (512 % 8 == 0): each XCD gets 64
  // contiguous logical ids = 2 full output-block-columns (its 10 wt blocks
  // = 1.25 MiB stay L2-hot across all 32 m-tiles).
  const int bx  = blockIdx.x;
  const int swz = (bx & 7) * 64 + (bx >> 3);
  const int ob  = swz >> 5;            // 0..15
  const int mt0 = swz & 31;            // 0..31
  const int m0  = mt0 * BM;
  const int n0g = ob * 256;

  int wbase[ABPI], gcol[ABPI];
  #pragma unroll
  for (int s = 0; s < ABPI; ++s) {
    int fi = __builtin_amdgcn_readfirstlane(fidx[ob * ABPI + s]);  // fi = g*5 + a
    wbase[s] = fi * (BS * BS);
    gcol[s]  = (fi / ABPI) * BS;
  }

  // staging constants: each issue covers 64 rows x 8 chunks of 16 B; logical
  // k-chunk lc staged at physical slot sc with lc = sc ^ (row&7) (0-conflict)
  const int sr = tid >> 3;
  const int sc = tid & 7;
  const int lc = sc ^ (sr & 7);
  const int tid16 = tid * 16;
  const unsigned short* pA0 = xb + (size_t)(m0 +   0 + sr) * IN_F + lc * 8;
  const unsigned short* pA1 = xb + (size_t)(m0 +  64 + sr) * IN_F + lc * 8;
  const unsigned short* pA2 = xb + (size_t)(m0 + 128 + sr) * IN_F + lc * 8;
  const unsigned short* pA3 = xb + (size_t)(m0 + 192 + sr) * IN_F + lc * 8;
  const unsigned short* pB0 = wt + (  0 + sr) * BS + lc * 8;
  const unsigned short* pB1 = wt + ( 64 + sr) * BS + lc * 8;
  const unsigned short* pB2 = wt + (128 + sr) * BS + lc * 8;
  const unsigned short* pB3 = wt + (192 + sr) * BS + lc * 8;

  // fragment-read constants: 8 waves 2M x 4N; per-wave 128 m x 64 n
  const int lane = tid & 63;
  const int wv   = tid >> 6;
  const int wm   = (wv >> 2) * 128;    // 0 or 128
  const int wn   = (wv & 3) * 64;      // 0,64,128,192
  const int lrow = lane & 15;
  const int quad = lane >> 4;
  const int rAb  = (wm + lrow) * 128;  // byte; A row stride 128 B
  const int rBb  = (wn + lrow) * 128;
  const int c0   = ((quad)     ^ (lrow & 7)) * 16;
  const int c1   = ((quad + 4) ^ (lrow & 7)) * 16;

  short8 af[4][2], bf01[2][2], bf23[2][2];
  floatx4 acc[8][4] = {};

  // ---- prologue: stage K-tile 0 fully into buf0, drain once ----
  {
    const int uA0 = gcol[0], uB0 = wbase[0];
    async16(pA0 + uA0, b0A         + tid16);
    async16(pA1 + uA0, b0A +  8192 + tid16);
    async16(pA2 + uA0, b0A + 16384 + tid16);
    async16(pA3 + uA0, b0A + 24576 + tid16);
    async16(pB0 + uB0, b0B         + tid16);
    async16(pB1 + uB0, b0B +  8192 + tid16);
    async16(pB2 + uB0, b0B + 16384 + tid16);
    async16(pB3 + uB0, b0B + 24576 + tid16);
    asm volatile("s_waitcnt vmcnt(0)" ::: "memory");
    __builtin_amdgcn_sched_barrier(0);
    __builtin_amdgcn_s_barrier();
  }

  // ---- main loop: K = 1280 = 20 K-tiles; tile t computes buf t&1, stages t+1 ----
  #pragma unroll 1
  for (int j = 0; j < 9; ++j) {
    const int t = j * 2;
    KTILE(t,     b0A, b0B, b1A, b1B, true, false);
    KTILE(t + 1, b1A, b1B, b0A, b0B, true, false);
  }
  KTILE(18, b0A, b0B, b1A, b1B, true, false);
  KTILE(19, b1A, b1B, b0A, b0B, false, true);

  // ---- epilogue: C/D layout col=lane&15, row=quad*4+reg (m89-verified) ----
  #pragma unroll
  for (int m = 0; m < 8; ++m) {
    const int row = m0 + wm + (m >> 2) * 64 + (m & 3) * 16 + quad * 4;
    #pragma unroll
    for (int n = 0; n < 4; ++n) {
      const int col = n0g + wn + n * 16 + lrow;
      float* po = out + (size_t)row * OUT_F + col;
      #pragma unroll
      for (int r = 0; r < 4; ++r)
        po[(size_t)r * OUT_F] = acc[m][n][r];
    }
  }
}

extern "C" void kernel_launch(void* const* d_in, const int* in_sizes, int n_in,
                              void* d_out, int out_size, void* d_ws, size_t ws_size,
                              hipStream_t stream) {
  const float* x  = (const float*)d_in[0];          // [8192][4096]
  const float* w  = (const float*)d_in[1];          // [4096][5][256]
  const int* fidx = (const int*)d_in[2];            // [16][5]
  float* out = (float*)d_out;

  unsigned short* xb = (unsigned short*)d_ws;
  unsigned short* wt = xb + (size_t)N_TOK * IN_F;

  static int smem_set = 0;
  if (!smem_set) {
    hipFuncSetAttribute((const void*)bfly_gemm,
                        hipFuncAttributeMaxDynamicSharedMemorySize, SMEM_TOTAL);
    smem_set = 1;
  }

  cvt_x_kernel<<<2048, 256, 0, stream>>>((const float4*)x, (ushort4v*)xb);
  cvt_w_kernel<<<NFLAT * 16, 256, 0, stream>>>(w, wt);
  bfly_gemm<<<16 * 32, 512, SMEM_TOTAL, stream>>>(xb, wt, fidx, out);
}

// Round 6
// 324.704 us; speedup vs baseline: 1.0099x; 1.0099x over previous
//
#include <hip/hip_runtime.h>
#include <stdint.h>

// Problem constants (fixed by the reference)
#define N_TOK 8192
#define IN_F 4096
#define OUT_F 4096
#define BS 256
#define ABPI 5
#define NFLAT 80          // 16 output blocks x 5 slots = all (g,a) pairs

typedef __attribute__((ext_vector_type(8))) short short8;    // 8 bf16 = 4 VGPRs (MFMA A/B frag)
typedef __attribute__((ext_vector_type(4))) float floatx4;   // MFMA C/D frag
typedef __attribute__((ext_vector_type(4))) unsigned short ushort4v;

__device__ __forceinline__ unsigned short f2bf(float f) {
  union { float f; unsigned int u; } v; v.f = f;
  unsigned int r = v.u + 0x7FFFu + ((v.u >> 16) & 1u);   // RNE
  return (unsigned short)(r >> 16);
}

__device__ __forceinline__ void async16(const void* g, void* l) {
  __builtin_amdgcn_global_load_lds((const __attribute__((address_space(1))) void*)g,
                                   (__attribute__((address_space(3))) void*)l, 16, 0, 0);
}

// ---------------- kernel 1: x fp32 -> bf16 (pure-coalesced grid-stride) -------
__global__ void cvt_x_kernel(const float4* __restrict__ x, ushort4v* __restrict__ xb) {
  int idx = blockIdx.x * 256 + threadIdx.x;       // one float4 -> ushort4 per iter
  const int stride = 2048 * 256;
  #pragma unroll
  for (int i = 0; i < 16; ++i, idx += stride) {   // 8192*4096/4 = 16 * 2048*256
    float4 a = x[idx];
    ushort4v o;
    o[0] = f2bf(a.x); o[1] = f2bf(a.y); o[2] = f2bf(a.z); o[3] = f2bf(a.w);
    xb[idx] = o;
  }
}

// ---------------- kernel 2: weight fp32 -> bf16, transposed per (g,a) block ----
__global__ void cvt_w_kernel(const float* __restrict__ w, unsigned short* __restrict__ wt) {
  __shared__ unsigned short tile[64][68];
  int b = blockIdx.x;
  int fi = b >> 4;
  int t  = b & 15;
  int k0 = (t >> 2) * 64, o0 = (t & 3) * 64;
  int g = fi / ABPI, a = fi % ABPI;
  int tid = threadIdx.x;
  int tr = tid >> 4, tc = tid & 15;
  #pragma unroll
  for (int i = 0; i < 4; ++i) {
    int k = k0 + i * 16 + tr;
    const float* src = w + (size_t)(g * 256 + k) * (ABPI * BS) + a * BS + o0 + tc * 4;
    float4 v = *(const float4*)src;
    tile[tc * 4 + 0][i * 16 + tr] = f2bf(v.x);
    tile[tc * 4 + 1][i * 16 + tr] = f2bf(v.y);
    tile[tc * 4 + 2][i * 16 + tr] = f2bf(v.z);
    tile[tc * 4 + 3][i * 16 + tr] = f2bf(v.w);
  }
  __syncthreads();
  #pragma unroll
  for (int i = 0; i < 4; ++i) {
    int o = i * 16 + tr;
    unsigned short* dst = wt + (size_t)fi * (BS * BS) + (size_t)(o0 + o) * BS + k0 + tc * 4;
    *(ushort4v*)dst = *(const ushort4v*)&tile[o][tc * 4];
  }
}

// ---------------- kernel 3: butterfly block-sparse GEMM ------------------------
// 256x256 tile, 8 waves (2M x 4N), per-wave 128x64, BK=64, double-buffered LDS,
// ONE barrier per K-tile. Fine-grained schedule: ds_reads issued in consumption
// order (groups pinned by sched_barrier), lgkmcnt stepped down 12/8/4/0 and
// 6/4/2/0 so the first MFMA starts after ~4 reads and LDS work slides under the
// MFMA pipe drain continuously (no post-barrier read ramp).
// Hazards: stages for t+1 (tile top) -> buf c^1, whose t-1 readers finished at
// the entry barrier; vmcnt(0)+barrier at tile end certifies t+1 before use.

#define BM 256
#define BN 256
#define BK 64
#define ABYTES 32768              // 256 rows x 128 B
#define BUFBYTES 65536            // A + B
#define SMEM_TOTAL 131072         // 2 buffers

#define SB() __builtin_amdgcn_sched_barrier(0)
#define PRIO1() __builtin_amdgcn_s_setprio(1)
#define PRIO0() __builtin_amdgcn_s_setprio(0)
#define LGKM(n) do { asm volatile("s_waitcnt lgkmcnt(" #n ")" ::: "memory"); SB(); } while (0)

__device__ __forceinline__ void ld_frag(const char* q, int c0, int c1, short8 (&f)[2]) {
  f[0] = *(const short8*)(q + c0);
  f[1] = *(const short8*)(q + c1);
}

__device__ __forceinline__ void mma2(const short8 (&a)[2], const short8 (&b)[2], floatx4& c) {
  c = __builtin_amdgcn_mfma_f32_16x16x32_bf16(a[0], b[0], c, 0, 0, 0);
  c = __builtin_amdgcn_mfma_f32_16x16x32_bf16(a[1], b[1], c, 0, 0, 0);
}

// One K-tile. Reads buf (Ab,Bb); stages tile t+1 into (Asd,Bsd) at offsets uA/uB.
#define KTILE(Ab, Bb, Asd, Bsd, uA, uB, DOSTAGE, ENDSYNC)                      \
  do {                                                                         \
    if (DOSTAGE) {                                                             \
      async16(pA0 + (uA), (Asd)         + tid16);                              \
      async16(pA1 + (uA), (Asd) +  8192 + tid16);                              \
      async16(pA2 + (uA), (Asd) + 16384 + tid16);                              \
      async16(pA3 + (uA), (Asd) + 24576 + tid16);                              \
      async16(pB0 + (uB), (Bsd)         + tid16);                              \
      async16(pB1 + (uB), (Bsd) +  8192 + tid16);                              \
      async16(pB2 + (uB), (Bsd) + 16384 + tid16);                              \
      async16(pB3 + (uB), (Bsd) + 24576 + tid16);                              \
    }                                                                          \
    SB();                                                                      \
    /* issue in consumption order; group boundaries pinned for lgkm counts */  \
    ld_frag((Ab) + rAb,        c0, c1, af[0]);                                 \
    ld_frag((Bb) + rBb,        c0, c1, bf01[0]); SB();                         \
    ld_frag((Ab) + rAb + 2048, c0, c1, af[1]);                                 \
    ld_frag((Bb) + rBb + 2048, c0, c1, bf01[1]); SB();                         \
    ld_frag((Ab) + rAb + 4096, c0, c1, af[2]);                                 \
    ld_frag((Ab) + rAb + 6144, c0, c1, af[3]);   SB();                         \
    ld_frag((Bb) + rBb + 4096, c0, c1, bf23[0]);                               \
    ld_frag((Bb) + rBb + 6144, c0, c1, bf23[1]); SB();                         \
    LGKM(12);                                                                  \
    PRIO1(); mma2(af[0], bf01[0], acc[0][0]); PRIO0();                         \
    LGKM(8);                                                                   \
    PRIO1(); mma2(af[0], bf01[1], acc[0][1]);                                  \
             mma2(af[1], bf01[0], acc[1][0]);                                  \
             mma2(af[1], bf01[1], acc[1][1]); PRIO0();                         \
    LGKM(4);                                                                   \
    PRIO1(); mma2(af[2], bf01[0], acc[2][0]);                                  \
             mma2(af[2], bf01[1], acc[2][1]);                                  \
             mma2(af[3], bf01[0], acc[3][0]);                                  \
             mma2(af[3], bf01[1], acc[3][1]); PRIO0();                         \
    LGKM(0);                                                                   \
    PRIO1(); mma2(af[0], bf23[0], acc[0][2]);                                  \
             mma2(af[0], bf23[1], acc[0][3]);                                  \
             mma2(af[1], bf23[0], acc[1][2]);                                  \
             mma2(af[1], bf23[1], acc[1][3]);                                  \
             mma2(af[2], bf23[0], acc[2][2]);                                  \
             mma2(af[2], bf23[1], acc[2][3]);                                  \
             mma2(af[3], bf23[0], acc[3][2]);                                  \
             mma2(af[3], bf23[1], acc[3][3]); PRIO0(); SB();                   \
    /* m-half1 reads, one mt-group at a time, stepped waits */                 \
    ld_frag((Ab) + rAb +  8192, c0, c1, af[0]); SB();                          \
    ld_frag((Ab) + rAb + 10240, c0, c1, af[1]); SB();                          \
    ld_frag((Ab) + rAb + 12288, c0, c1, af[2]); SB();                          \
    ld_frag((Ab) + rAb + 14336, c0, c1, af[3]); SB();                          \
    LGKM(6);                                                                   \
    PRIO1(); mma2(af[0], bf23[0], acc[4][2]);                                  \
             mma2(af[0], bf23[1], acc[4][3]);                                  \
             mma2(af[0], bf01[0], acc[4][0]);                                  \
             mma2(af[0], bf01[1], acc[4][1]); PRIO0();                         \
    LGKM(4);                                                                   \
    PRIO1(); mma2(af[1], bf23[0], acc[5][2]);                                  \
             mma2(af[1], bf23[1], acc[5][3]);                                  \
             mma2(af[1], bf01[0], acc[5][0]);                                  \
             mma2(af[1], bf01[1], acc[5][1]); PRIO0();                         \
    LGKM(2);                                                                   \
    PRIO1(); mma2(af[2], bf23[0], acc[6][2]);                                  \
             mma2(af[2], bf23[1], acc[6][3]);                                  \
             mma2(af[2], bf01[0], acc[6][0]);                                  \
             mma2(af[2], bf01[1], acc[6][1]); PRIO0();                         \
    LGKM(0);                                                                   \
    PRIO1(); mma2(af[3], bf23[0], acc[7][2]);                                  \
             mma2(af[3], bf23[1], acc[7][3]);                                  \
             mma2(af[3], bf01[0], acc[7][0]);                                  \
             mma2(af[3], bf01[1], acc[7][1]); PRIO0();                         \
    if (ENDSYNC) {                                                             \
      asm volatile("s_waitcnt vmcnt(0)" ::: "memory"); SB();                   \
      __builtin_amdgcn_s_barrier();                                            \
    }                                                                          \
  } while (0)

__global__ __launch_bounds__(512, 2)
void bfly_gemm(const unsigned short* __restrict__ xb,   // [8192][4096] bf16
               const unsigned short* __restrict__ wt,   // [80][256 o][256 k] bf16
               const int* __restrict__ fidx,            // [16][5]
               float* __restrict__ out)                 // [8192][4096] fp32
{
  extern __shared__ __align__(16) char smem[];
  char* const b0A = smem;
  char* const b0B = b0A + ABYTES;
  char* const b1A = smem + BUFBYTES;
  char* const b1B = b1A + ABYTES;

  const int tid = threadIdx.x;
  // 512 blocks; bijective XCD swizzle (512 % 8 == 0): each XCD gets 64
  // contiguous logical ids = 2 full output-block-columns (its 10 wt blocks
  // = 1.25 MiB stay L2-hot across all 32 m-tiles).
  const int bx  = blockIdx.x;
  const int swz = (bx & 7) * 64 + (bx >> 3);
  const int ob  = swz >> 5;            // 0..15
  const int mt0 = swz & 31;            // 0..31
  const int m0  = mt0 * BM;
  const int n0g = ob * 256;

  int wbase[ABPI], gcol[ABPI];
  #pragma unroll
  for (int s = 0; s < ABPI; ++s) {
    int fi = __builtin_amdgcn_readfirstlane(fidx[ob * ABPI + s]);  // fi = g*5 + a
    wbase[s] = fi * (BS * BS);
    gcol[s]  = (fi / ABPI) * BS;
  }

  // staging constants: each issue covers 64 rows x 8 chunks of 16 B; logical
  // k-chunk lc staged at physical slot sc with lc = sc ^ (row&7) (0-conflict)
  const int sr = tid >> 3;
  const int sc = tid & 7;
  const int lc = sc ^ (sr & 7);
  const int tid16 = tid * 16;
  const unsigned short* pA0 = xb + (size_t)(m0 +   0 + sr) * IN_F + lc * 8;
  const unsigned short* pA1 = xb + (size_t)(m0 +  64 + sr) * IN_F + lc * 8;
  const unsigned short* pA2 = xb + (size_t)(m0 + 128 + sr) * IN_F + lc * 8;
  const unsigned short* pA3 = xb + (size_t)(m0 + 192 + sr) * IN_F + lc * 8;
  const unsigned short* pB0 = wt + (  0 + sr) * BS + lc * 8;
  const unsigned short* pB1 = wt + ( 64 + sr) * BS + lc * 8;
  const unsigned short* pB2 = wt + (128 + sr) * BS + lc * 8;
  const unsigned short* pB3 = wt + (192 + sr) * BS + lc * 8;

  // fragment-read constants: 8 waves 2M x 4N; per-wave 128 m x 64 n
  const int lane = tid & 63;
  const int wv   = tid >> 6;
  const int wm   = (wv >> 2) * 128;    // 0 or 128
  const int wn   = (wv & 3) * 64;      // 0,64,128,192
  const int lrow = lane & 15;
  const int quad = lane >> 4;
  const int rAb  = (wm + lrow) * 128;  // byte; A row stride 128 B
  const int rBb  = (wn + lrow) * 128;
  const int c0   = ((quad)     ^ (lrow & 7)) * 16;
  const int c1   = ((quad + 4) ^ (lrow & 7)) * 16;

  short8 af[4][2], bf01[2][2], bf23[2][2];
  floatx4 acc[8][4] = {};

  // ---- prologue: stage K-tile 0 fully into buf0, drain once ----
  {
    const int uA0 = gcol[0], uB0 = wbase[0];
    async16(pA0 + uA0, b0A         + tid16);
    async16(pA1 + uA0, b0A +  8192 + tid16);
    async16(pA2 + uA0, b0A + 16384 + tid16);
    async16(pA3 + uA0, b0A + 24576 + tid16);
    async16(pB0 + uB0, b0B         + tid16);
    async16(pB1 + uB0, b0B +  8192 + tid16);
    async16(pB2 + uB0, b0B + 16384 + tid16);
    async16(pB3 + uB0, b0B + 24576 + tid16);
    asm volatile("s_waitcnt vmcnt(0)" ::: "memory");
    SB();
    __builtin_amdgcn_s_barrier();
  }

  // ---- main loop: 20 K-tiles = 5 groups of 4 (group-uniform gather bases,
  //      hoisted to scalars so the tile body has no runtime array indexing) ----
  #pragma unroll 1
  for (int s = 0; s < 4; ++s) {
    const int uAg = gcol[s],     uBg = wbase[s];
    const int uAn = gcol[s + 1], uBn = wbase[s + 1];
    KTILE(b0A, b0B, b1A, b1B, uAg +  64, uBg +  64, true, true);
    KTILE(b1A, b1B, b0A, b0B, uAg + 128, uBg + 128, true, true);
    KTILE(b0A, b0B, b1A, b1B, uAg + 192, uBg + 192, true, true);
    KTILE(b1A, b1B, b0A, b0B, uAn,       uBn,       true, true);
  }
  { // group 4: tiles 16..19
    const int uAg = gcol[4], uBg = wbase[4];
    KTILE(b0A, b0B, b1A, b1B, uAg +  64, uBg +  64, true, true);
    KTILE(b1A, b1B, b0A, b0B, uAg + 128, uBg + 128, true, true);
    KTILE(b0A, b0B, b1A, b1B, uAg + 192, uBg + 192, true, true);
    KTILE(b1A, b1B, b0A, b0B, 0,         0,         false, false);
  }

  // ---- epilogue: C/D layout col=lane&15, row=quad*4+reg (m89-verified) ----
  #pragma unroll
  for (int m = 0; m < 8; ++m) {
    const int row = m0 + wm + (m >> 2) * 64 + (m & 3) * 16 + quad * 4;
    #pragma unroll
    for (int n = 0; n < 4; ++n) {
      const int col = n0g + wn + n * 16 + lrow;
      float* po = out + (size_t)row * OUT_F + col;
      #pragma unroll
      for (int r = 0; r < 4; ++r)
        po[(size_t)r * OUT_F] = acc[m][n][r];
    }
  }
}

extern "C" void kernel_launch(void* const* d_in, const int* in_sizes, int n_in,
                              void* d_out, int out_size, void* d_ws, size_t ws_size,
                              hipStream_t stream) {
  const float* x  = (const float*)d_in[0];          // [8192][4096]
  const float* w  = (const float*)d_in[1];          // [4096][5][256]
  const int* fidx = (const int*)d_in[2];            // [16][5]
  float* out = (float*)d_out;

  unsigned short* xb = (unsigned short*)d_ws;
  unsigned short* wt = xb + (size_t)N_TOK * IN_F;

  static int smem_set = 0;
  if (!smem_set) {
    hipFuncSetAttribute((const void*)bfly_gemm,
                        hipFuncAttributeMaxDynamicSharedMemorySize, SMEM_TOTAL);
    smem_set = 1;
  }

  cvt_x_kernel<<<2048, 256, 0, stream>>>((const float4*)x, (ushort4v*)xb);
  cvt_w_kernel<<<NFLAT * 16, 256, 0, stream>>>(w, wt);
  bfly_gemm<<<16 * 32, 512, SMEM_TOTAL, stream>>>(xb, wt, fidx, out);
}